// Round 5
// baseline (1544.720 us; speedup 1.0000x reference)
//
#include <hip/hip_runtime.h>

#define NPTS   300000
#define NPAIRS 100000
#define KOFF   27
#define NTOT   (KOFF * NPAIRS)      /* 2,700,000 */
#define CIN    32
#define COUT   64
#define NGROUP 8
#define EPSV   1e-5f
#define SLOPE  0.01f

#define RB_SIZE 256                  /* rows per conv block */
#define NRB     ((NPTS + RB_SIZE - 1) / RB_SIZE)   /* 1172 */
#define NBUK    (NRB * KOFF)                        /* 31,644 buckets */
#define NB2     ((NBUK + 1023) / 1024)              /* 31 scan blocks */

#define PAIRS_PER_BLOCK 256
#define BLOCKS_PER_K ((NPAIRS + PAIRS_PER_BLOCK - 1) / PAIRS_PER_BLOCK)

/* ---- workspace layout ---- */
#define OFS_STATS  0u
#define OFS_PART   4096u
#define OFS_CURSOR 8192u                          /* NBUK*4 = 126,576 */
#define OFS_WPK    (OFS_CURSOR + 131072u)         /* 27*16*64*4 = 110,592 */
#define OFS_ENT    (OFS_WPK + 114688u)            /* 2.7M*4 = 10,800,000 */
#define OFS_FH16   (OFS_ENT + 10800128u)          /* 64-aligned */
#define WS_MAIN    ((size_t)OFS_FH16 + 19200000u) /* ~30.3 MB (fits: 31.3MB path ran) */

/* ---- f16 helpers ---- */
typedef _Float16 half2v __attribute__((ext_vector_type(2)));

__device__ inline unsigned pack_h2(float a, float b) {
    union { _Float16 h[2]; unsigned u; } x;
    x.h[0] = (_Float16)a; x.h[1] = (_Float16)b;
    return x.u;
}
__device__ inline half2v as_h2(unsigned u) {
    union { unsigned u; half2v h; } x; x.u = u; return x.h;
}
__device__ inline float dot2_h(unsigned a, unsigned b, float c) {
#if __has_builtin(__builtin_amdgcn_fdot2)
    return __builtin_amdgcn_fdot2(as_h2(a), as_h2(b), c, false);
#else
    half2v ha = as_h2(a), hb = as_h2(b);
    c = fmaf((float)ha.x, (float)hb.x, c);
    return fmaf((float)ha.y, (float)hb.y, c);
#endif
}

/* ================= prep: feats->f16, weights->packed f16, zero cursor/stats ================= */
__global__ __launch_bounds__(256) void prep_kernel(const float2* __restrict__ src, int n2,
                                                   unsigned* __restrict__ fh16,
                                                   const float* __restrict__ weight,
                                                   unsigned* __restrict__ wpk,
                                                   int* __restrict__ cursor,
                                                   float* __restrict__ stats) {
    int i = blockIdx.x * 256 + threadIdx.x;
    if (i < n2) { float2 v = src[i]; fh16[i] = pack_h2(v.x, v.y); }
    if (i < KOFF * 16 * 64) {
        int k = i >> 10, rem = i & 1023, j = rem >> 6, c = rem & 63;
        const float* wp = weight + k * (CIN * COUT) + (2 * j) * COUT + c;
        wpk[i] = pack_h2(wp[0], wp[COUT]);
    }
    if (i < NBUK) cursor[i] = 0;
    if (i < 16) stats[i] = 0.f;
}

/* ================= histogram over (rowblock, k) buckets ================= */
__global__ __launch_bounds__(256) void hist_kernel(const int* __restrict__ oi,
                                                   int* __restrict__ cursor) {
    int i = blockIdx.x * 256 + threadIdx.x;
    if (i < NTOT) {
        int k = i / NPAIRS;
        int r = oi[i];
        atomicAdd(cursor + ((r >> 8) * KOFF + k), 1);
    }
}

/* ================= scan (31,644 elements, 3 stages) ================= */
__global__ __launch_bounds__(256) void reduce_blocks_kernel(const int* __restrict__ cursor,
                                                            int* __restrict__ part) {
    __shared__ int sm[256];
    int tid = threadIdx.x, i0 = blockIdx.x * 1024 + tid * 4;
    int s = 0;
#pragma unroll
    for (int j = 0; j < 4; ++j) if (i0 + j < NBUK) s += cursor[i0 + j];
    sm[tid] = s; __syncthreads();
    for (int off = 128; off; off >>= 1) {
        if (tid < off) sm[tid] += sm[tid + off];
        __syncthreads();
    }
    if (tid == 0) part[blockIdx.x] = sm[0];
}

__global__ __launch_bounds__(64) void scan_partials_kernel(int* __restrict__ part) {
    int tid = threadIdx.x;
    int o = (tid < NB2) ? part[tid] : 0;
    int v = o;
#pragma unroll
    for (int off = 1; off < 64; off <<= 1) {
        int t = __shfl_up(v, off, 64);
        if (tid >= off) v += t;
    }
    if (tid < NB2) part[tid] = v - o;   /* exclusive */
}

__global__ __launch_bounds__(256) void scan_apply_kernel(int* __restrict__ cursor,
                                                         const int* __restrict__ part) {
    __shared__ int sm[256];
    int tid = threadIdx.x, i0 = blockIdx.x * 1024 + tid * 4;
    int c0 = 0, c1 = 0, c2 = 0, c3 = 0;
    if (i0 + 0 < NBUK) c0 = cursor[i0 + 0];
    if (i0 + 1 < NBUK) c1 = cursor[i0 + 1];
    if (i0 + 2 < NBUK) c2 = cursor[i0 + 2];
    if (i0 + 3 < NBUK) c3 = cursor[i0 + 3];
    int s = c0 + c1 + c2 + c3;
    sm[tid] = s; __syncthreads();
    for (int off = 1; off < 256; off <<= 1) {
        int t = (tid >= off) ? sm[tid - off] : 0;
        __syncthreads();
        sm[tid] += t;
        __syncthreads();
    }
    int excl = sm[tid] - s + part[blockIdx.x];
    if (i0 + 0 < NBUK) cursor[i0 + 0] = excl;
    if (i0 + 1 < NBUK) cursor[i0 + 1] = excl + c0;
    if (i0 + 2 < NBUK) cursor[i0 + 2] = excl + c0 + c1;
    if (i0 + 3 < NBUK) cursor[i0 + 3] = excl + c0 + c1 + c2;
}

/* entries[slot] = rin | localrow<<19 ; after this, cursor[b] = bucket end */
__global__ __launch_bounds__(256) void fill_kernel(const int* __restrict__ oi,
                                                   const int* __restrict__ ii,
                                                   int* __restrict__ cursor,
                                                   unsigned* __restrict__ entries) {
    int i = blockIdx.x * 256 + threadIdx.x;
    if (i < NTOT) {
        int k = i / NPAIRS;
        int r = oi[i];
        int slot = atomicAdd(cursor + ((r >> 8) * KOFF + k), 1);
        entries[slot] = (unsigned)ii[i] | ((unsigned)(r & 255) << 19);
    }
}

/* ================= bucketed conv: LDS fp32 accumulators, register f16 weights =================
 * Block owns 256 output rows (64KB LDS acc -> 2 blocks/CU). Wave w handles
 * k = w and w+16; its weight column lives in 16 VGPRs (wave-varying k, can't
 * be uniform-sunk). Per entry: 4 uniform dwordx4 feats loads + 16 v_dot2 +
 * 1 conflict-free ds_add_f32  (vs round-4's 16 ds_read_b32 = the 397us).
 * Entries vector-loaded 64/chunk + shfl (kills serial scalar-load chain).
 * Epilogue: coalesced out write + fused group stats.
 */
__global__ __launch_bounds__(1024) void conv_bucket_kernel(
    const unsigned* __restrict__ fh16, const unsigned* __restrict__ wpk,
    const unsigned* __restrict__ entries, const int* __restrict__ cursor,
    float* __restrict__ out, float* __restrict__ stats)
{
    __shared__ float4 smv[RB_SIZE * COUT / 4];   /* 64 KB */
    float* sm = (float*)smv;
    const int tid  = threadIdx.x;
    const int lane = tid & 63;
    const int wv   = tid >> 6;

#pragma unroll
    for (int j = 0; j < 4; ++j)
        smv[tid + j * 1024] = make_float4(0.f, 0.f, 0.f, 0.f);
    __syncthreads();

    const int rb = blockIdx.x;

    for (int kk = wv; kk < KOFF; kk += 16) {
        int key = rb * KOFF + kk;
        int s = (key == 0) ? 0 : cursor[key - 1];
        int e = cursor[key];
        s = __builtin_amdgcn_readfirstlane(s);
        e = __builtin_amdgcn_readfirstlane(e);
        if (s >= e) continue;

        unsigned w[16];
        const unsigned* wp = wpk + (kk << 10) + lane;
#pragma unroll
        for (int j = 0; j < 16; ++j) w[j] = wp[j << 6];

        for (int base = s; base < e; base += 64) {
            int nv = e - base; if (nv > 64) nv = 64;
            unsigned entv = 0;
            if (base + lane < e) entv = entries[base + lane];
#pragma unroll 2
            for (int t = 0; t < nv; ++t) {
                unsigned ent = __shfl(entv, t, 64);
                const uint4* fr = (const uint4*)(fh16 + (size_t)(ent & 0x7FFFFu) * 16);
                uint4 fa = fr[0], fb = fr[1], fc = fr[2], fd = fr[3];
                float acc = 0.f;
                acc = dot2_h(fa.x, w[0],  acc);
                acc = dot2_h(fa.y, w[1],  acc);
                acc = dot2_h(fa.z, w[2],  acc);
                acc = dot2_h(fa.w, w[3],  acc);
                acc = dot2_h(fb.x, w[4],  acc);
                acc = dot2_h(fb.y, w[5],  acc);
                acc = dot2_h(fb.z, w[6],  acc);
                acc = dot2_h(fb.w, w[7],  acc);
                acc = dot2_h(fc.x, w[8],  acc);
                acc = dot2_h(fc.y, w[9],  acc);
                acc = dot2_h(fc.z, w[10], acc);
                acc = dot2_h(fc.w, w[11], acc);
                acc = dot2_h(fd.x, w[12], acc);
                acc = dot2_h(fd.y, w[13], acc);
                acc = dot2_h(fd.z, w[14], acc);
                acc = dot2_h(fd.w, w[15], acc);
                int lr = (int)(ent >> 19);
                atomicAdd(&sm[(lr << 6) + lane], acc);   /* ds_add_f32, conflict-free */
            }
        }
    }
    __syncthreads();

    /* out write + fused group stats */
    float ssum = 0.f, ssq = 0.f;
    int r0 = rb << 8;
    for (int lr = wv; lr < RB_SIZE; lr += 16) {
        int gr = r0 + lr;
        if (gr < NPTS) {
            float v = sm[(lr << 6) + lane];
            out[(size_t)gr * COUT + lane] = v;
            ssum += v; ssq += v * v;
        }
    }
#pragma unroll
    for (int m = 1; m < 8; m <<= 1) {
        ssum += __shfl_xor(ssum, m, 64);
        ssq  += __shfl_xor(ssq,  m, 64);
    }
    if ((lane & 7) == 0) {
        atomicAdd(stats + (lane >> 3),     ssum);
        atomicAdd(stats + 8 + (lane >> 3), ssq);
    }
}

/* ================= normalize + affine + leaky relu ================= */
__global__ __launch_bounds__(256) void norm_kernel(float4* __restrict__ out4, int n4,
                                                   const float* __restrict__ stats,
                                                   const float* __restrict__ gamma,
                                                   const float* __restrict__ beta) {
    int i = blockIdx.x * blockDim.x + threadIdx.x;
    if (i >= n4) return;
    int c0 = (i & 15) * 4;
    int g  = c0 >> 3;
    const float cnt = (float)NPTS * (COUT / NGROUP);
    float mean = stats[g] / cnt;
    float var  = stats[8 + g] / cnt - mean * mean;
    float inv  = rsqrtf(var + EPSV);
    float4 v  = out4[i];
    float4 ga = *(const float4*)(gamma + c0);
    float4 be = *(const float4*)(beta  + c0);
    float x;
    x = (v.x - mean) * inv * ga.x + be.x; v.x = x >= 0.f ? x : SLOPE * x;
    x = (v.y - mean) * inv * ga.y + be.y; v.y = x >= 0.f ? x : SLOPE * x;
    x = (v.z - mean) * inv * ga.z + be.z; v.z = x >= 0.f ? x : SLOPE * x;
    x = (v.w - mean) * inv * ga.w + be.w; v.w = x >= 0.f ? x : SLOPE * x;
    out4[i] = v;
}

/* ================= fallback (atomic fp32 path, tiny ws) ================= */
__global__ __launch_bounds__(256) void zero_kernel(float4* __restrict__ out4, int n4,
                                                   float* __restrict__ stats) {
    int i = blockIdx.x * blockDim.x + threadIdx.x;
    if (i < n4) out4[i] = make_float4(0.f, 0.f, 0.f, 0.f);
    if (blockIdx.x == 0 && threadIdx.x < 16) stats[threadIdx.x] = 0.f;
}

__global__ __launch_bounds__(256) void conv_f32_kernel(
    const float* __restrict__ feats, const float* __restrict__ weight,
    const int* __restrict__ in_idx, const int* __restrict__ out_idx,
    float* __restrict__ out)
{
    const int lane = threadIdx.x & 63;
    const int wave = threadIdx.x >> 6;
    const int k     = blockIdx.x / BLOCKS_PER_K;
    const int pair0 = (blockIdx.x % BLOCKS_PER_K) * PAIRS_PER_BLOCK;
    float w[CIN];
    const float* wk = weight + k * (CIN * COUT) + lane;
#pragma unroll
    for (int i = 0; i < CIN; ++i) w[i] = wk[i * COUT];
    const int per_wave = PAIRS_PER_BLOCK / 4;
    int p = pair0 + wave * per_wave;
    int pend = p + per_wave; if (pend > NPAIRS) pend = NPAIRS;
    const int* ii = in_idx  + k * NPAIRS;
    const int* oi = out_idx + k * NPAIRS;
    for (; p < pend; ++p) {
        int rin  = __builtin_amdgcn_readfirstlane(ii[p]);
        int rout = __builtin_amdgcn_readfirstlane(oi[p]);
        const float* frow = feats + (size_t)rin * CIN;
        float acc = 0.f;
#pragma unroll
        for (int i = 0; i < CIN; ++i) acc = fmaf(frow[i], w[i], acc);
        atomicAdd(out + (size_t)rout * COUT + lane, acc);
    }
}

__global__ __launch_bounds__(256) void stats_kernel(const float* __restrict__ out,
                                                    float* __restrict__ stats) {
    const int c = threadIdx.x & 63;
    const int wave_in_grid = blockIdx.x * 4 + (threadIdx.x >> 6);
    const int nwaves = gridDim.x * 4;
    float s = 0.f, ss = 0.f;
    for (int r = wave_in_grid; r < NPTS; r += nwaves) {
        float v = out[(size_t)r * COUT + c];
        s += v; ss += v * v;
    }
#pragma unroll
    for (int m = 1; m < 8; m <<= 1) {
        s  += __shfl_xor(s,  m, 64);
        ss += __shfl_xor(ss, m, 64);
    }
    if ((c & 7) == 0) {
        atomicAdd(stats + (c >> 3),     s);
        atomicAdd(stats + 8 + (c >> 3), ss);
    }
}

/* ================= launch ================= */
extern "C" void kernel_launch(void* const* d_in, const int* in_sizes, int n_in,
                              void* d_out, int out_size, void* d_ws, size_t ws_size,
                              hipStream_t stream) {
    const float* feats   = (const float*)d_in[0];
    const float* weight  = (const float*)d_in[1];
    const float* gamma   = (const float*)d_in[2];
    const float* beta    = (const float*)d_in[3];
    const int*   in_idx  = (const int*)d_in[4];
    const int*   out_idx = (const int*)d_in[5];
    float* out = (float*)d_out;
    char*  ws  = (char*)d_ws;

    int n4 = out_size / 4;
    int zb = (n4 + 255) / 256;

    if (ws_size >= WS_MAIN) {
        float*    stats   = (float*)(ws + OFS_STATS);
        int*      part    = (int*)(ws + OFS_PART);
        int*      cursor  = (int*)(ws + OFS_CURSOR);
        unsigned* wpk     = (unsigned*)(ws + OFS_WPK);
        unsigned* entries = (unsigned*)(ws + OFS_ENT);
        unsigned* fh16    = (unsigned*)(ws + OFS_FH16);
        int n2 = NPTS * CIN / 2;

        prep_kernel<<<(n2 + 255) / 256, 256, 0, stream>>>((const float2*)feats, n2,
                                                          fh16, weight, wpk, cursor, stats);
        hist_kernel<<<(NTOT + 255) / 256, 256, 0, stream>>>(out_idx, cursor);
        reduce_blocks_kernel<<<NB2, 256, 0, stream>>>(cursor, part);
        scan_partials_kernel<<<1, 64, 0, stream>>>(part);
        scan_apply_kernel<<<NB2, 256, 0, stream>>>(cursor, part);
        fill_kernel<<<(NTOT + 255) / 256, 256, 0, stream>>>(out_idx, in_idx, cursor, entries);
        conv_bucket_kernel<<<NRB, 1024, 0, stream>>>(fh16, wpk, entries, cursor, out, stats);
        norm_kernel<<<zb, 256, 0, stream>>>((float4*)out, n4, stats, gamma, beta);
    } else {
        float* stats = (float*)(ws + OFS_STATS);
        zero_kernel<<<zb, 256, 0, stream>>>((float4*)out, n4, stats);
        conv_f32_kernel<<<KOFF * BLOCKS_PER_K, 256, 0, stream>>>(feats, weight, in_idx, out_idx, out);
        stats_kernel<<<2048, 256, 0, stream>>>(out, stats);
        norm_kernel<<<zb, 256, 0, stream>>>((float4*)out, n4, stats, gamma, beta);
    }
}